// Round 7
// baseline (375.384 us; speedup 1.0000x reference)
//
#include <hip/hip_runtime.h>
#include <hip/hip_bf16.h>
#include <math.h>

// Problem dims
#define B_  16
#define S_  4096
#define D_  256
#define H_  512
#define BS_ 65536           // B_*S_
#define BSH_ 33554432L      // BS_*H_
#define BSD_ 16777216L      // BS_*D_
#define CCH 128             // scan chunks
#define LCH 32              // chunk length (CCH*LCH == S_)
#define TPAD 136            // epilogue tile stride (272B row, 16B-aligned)

typedef __bf16 bf16;
typedef __bf16 bf16x8 __attribute__((ext_vector_type(8)));
typedef float  f32x4  __attribute__((ext_vector_type(4)));

#define AS1 __attribute__((address_space(1)))
#define AS3 __attribute__((address_space(3)))

__device__ __forceinline__ void gload_lds16(const void* g, void* l) {
  __builtin_amdgcn_global_load_lds((const AS1 void*)g, (AS3 void*)l, 16, 0, 0);
}

// ---- fast transcendentals (v_exp_f32 / v_rcp_f32; ~1ulp f32, fine for bf16 out) ----
#if __has_builtin(__builtin_amdgcn_exp2f)
#define EXP2F __builtin_amdgcn_exp2f
#else
#define EXP2F exp2f
#endif
#if __has_builtin(__builtin_amdgcn_rcpf)
#define RCPF __builtin_amdgcn_rcpf
#else
#define RCPF(x) (1.f/(x))
#endif
#define L2E 1.4426950408889634f

__device__ __forceinline__ float fsigmoid(float x) {
  return RCPF(1.f + EXP2F(-L2E * x));          // saturates to 0/1, no NaN
}
__device__ __forceinline__ float ftanh(float x) {
  return 2.f * RCPF(1.f + EXP2F(-2.f * L2E * x)) - 1.f;  // no NaN at +/-inf
}
__device__ __forceinline__ float fsilu(float x) {
  return x * RCPF(1.f + EXP2F(-L2E * x));
}

// ---------------- casts ----------------
__global__ void k_cast_x(const float* __restrict__ x, bf16* __restrict__ xb, int n8) {
  int i = blockIdx.x * blockDim.x + threadIdx.x;
  if (i >= n8) return;
  const float4* p = (const float4*)x + (long)i * 2;
  float4 a = p[0], b = p[1];
  bf16x8 o;
  o[0]=(bf16)a.x; o[1]=(bf16)a.y; o[2]=(bf16)a.z; o[3]=(bf16)a.w;
  o[4]=(bf16)b.x; o[5]=(bf16)b.y; o[6]=(bf16)b.z; o[7]=(bf16)b.w;
  ((bf16x8*)xb)[i] = o;
}

__global__ void k_cast_w(const float* __restrict__ in_w, const float* __restrict__ gate_w,
                         const float* __restrict__ pw_w,
                         bf16* __restrict__ w1, bf16* __restrict__ pw) {
  int i = blockIdx.x * blockDim.x + threadIdx.x;
  const int HD = H_ * D_;           // 131072
  if (i < HD)            w1[i] = (bf16)in_w[i];
  else if (i < 2 * HD)   w1[i] = (bf16)gate_w[i - HD];
  else {
    int j = i - 2 * HD;
    if (j < H_ * H_)     pw[j] = (bf16)pw_w[j];
  }
}

// ---------------- GEMM: 128x128 tile, BK=32, 8 waves (512 thr) ----------------
// Occupancy-first: per-wave acc = 4x2 frags (32 AGPR) so ~86 unified regs/wave
// -> ~6 waves/SIMD instead of ~2.5. K-loop: 2-deep LDS double-buffer with
// counted vmcnt + raw s_barrier (round-5 protocol, re-counted for 2 loads/STAGE).
// EPI==1: proj epilogue (h/g). EPI==2: pointwise u epilogue + FUSED scan1
// (per-chunk (A,B) reduction straight from the u tile in LDS).
template<int KDIM, int EPI>
__global__ __launch_bounds__(512, 5)
void k_gemm(const bf16* __restrict__ A, const bf16* __restrict__ Bw,
            const int* __restrict__ mask,
            const float* __restrict__ bias0, const float* __restrict__ bias1,
            const bf16* __restrict__ hbuf, const bf16* __restrict__ gbuf,
            const float* __restrict__ A_log, const float* __restrict__ Bp,
            float* __restrict__ Ac, float* __restrict__ Bc,
            bf16* __restrict__ out0, bf16* __restrict__ out1, int Ntiles)
{
  extern __shared__ char smem_raw[];            // 34816 B (2x16KB staging | epi tile)
  bf16* tile = (bf16*)smem_raw;

  const int t = threadIdx.x;
  const int w = t >> 6, lane = t & 63;
  const int nwg = gridDim.x;                    // XCD-aware swizzle (nwg % 8 == 0)
  const int wg = (blockIdx.x & 7) * (nwg >> 3) + (blockIdx.x >> 3);
  const int bn0 = (wg % Ntiles) * 128;
  const int bm0 = (wg / Ntiles) * 128;
  const int wm = w >> 2, wn = w & 3;            // 2 x 4 wave grid: 64-row x 32-col
  const int fr = lane & 15, kq = lane >> 4;
  constexpr int NT = KDIM / 32;                 // 8 (proj) / 16 (pw)

  // staging: thread t covers row t>>2 (0..127), k-seg (t&3)*8; LDS linear t*8 elems
  const bf16* Ag = A  + (long)(bm0 + (t >> 2)) * KDIM + (t & 3) * 8;
  const bf16* Bg = Bw + (long)(bn0 + (t >> 2)) * KDIM + (t & 3) * 8;

  f32x4 acc[4][2];
#pragma unroll
  for (int i = 0; i < 4; ++i)
#pragma unroll
    for (int j = 0; j < 2; ++j) acc[i][j] = (f32x4){0.f, 0.f, 0.f, 0.f};

  // stage k-tile tt into buffer tt&1 (A then B: 2 vmem ops per thread)
#define STAGE(tt)                                                           \
  { char* _b = smem_raw + ((tt) & 1) * 16384;                               \
    gload_lds16(Ag + (tt) * 32, (bf16*)_b + t * 8);                         \
    gload_lds16(Bg + (tt) * 32, (bf16*)(_b + 8192) + t * 8); }

  STAGE(0); STAGE(1);                           // 4 ops in flight

#pragma unroll
  for (int kt = 0; kt < NT; ++kt) {
    // own tile-kt loads (2) complete; tile kt+1's (2) may remain in flight
    if (kt + 1 < NT) asm volatile("s_waitcnt vmcnt(2)" ::: "memory");
    else             asm volatile("s_waitcnt vmcnt(0)" ::: "memory");
    __builtin_amdgcn_s_barrier();               // buf[kt&1] staged by ALL waves

    const bf16* As = (const bf16*)(smem_raw + (kt & 1) * 16384);
    const bf16* Bs = As + 4096;
    bf16x8 af[4], bfr[2];
#pragma unroll
    for (int mi = 0; mi < 4; ++mi)
      af[mi] = *(const bf16x8*)&As[(wm * 64 + mi * 16 + fr) * 32 + kq * 8];
#pragma unroll
    for (int ni = 0; ni < 2; ++ni)
      bfr[ni] = *(const bf16x8*)&Bs[(wn * 32 + ni * 16 + fr) * 32 + kq * 8];

    asm volatile("s_waitcnt lgkmcnt(0)" ::: "memory");  // own reads in regs
    __builtin_amdgcn_s_barrier();               // all waves' reads done -> buf reusable

    if (kt + 2 < NT) STAGE(kt + 2);             // refill freed buffer

#pragma unroll
    for (int mi = 0; mi < 4; ++mi)
#pragma unroll
      for (int ni = 0; ni < 2; ++ni)
        acc[mi][ni] = __builtin_amdgcn_mfma_f32_16x16x32_bf16(af[mi], bfr[ni], acc[mi][ni], 0, 0, 0);
  }
#undef STAGE

  __syncthreads();   // staging reads done everywhere before tile overwrite

  // ---- epilogue phase 1: activate + scatter into LDS tile ----
  const bool hside = (EPI != 1) || (bn0 < H_);
#pragma unroll
  for (int mi = 0; mi < 4; ++mi) {
#pragma unroll
    for (int rr = 0; rr < 4; ++rr) {
      const int row = wm * 64 + mi * 16 + kq * 4 + rr;
      const int gm = bm0 + row;
      float mf = 1.f;
      if (EPI == 1) mf = (mask[gm] != 0) ? 1.f : 0.f;
#pragma unroll
      for (int ni = 0; ni < 2; ++ni) {
        const int col = wn * 32 + ni * 16 + fr;
        float c = acc[mi][ni][rr];
        float val;
        if (EPI == 1) {
          const int gn = bn0 + col;
          val = hside ? ftanh(c + bias0[gn]) * mf
                      : fsigmoid(c + bias1[gn - H_]);
        } else {
          val = c + bias0[bn0 + col];   // defer hbuf add + silu to phase 2
        }
        tile[row * TPAD + col] = (bf16)val;
      }
    }
  }
  __syncthreads();

  // ---- epilogue phase 2: coalesced readback + wide store ----
  const int pr = t >> 4;            // 0..31
  const int pc = (t & 15) * 8;      // col element base
#pragma unroll
  for (int rr = 0; rr < 4; ++rr) {
    const int row = pr + rr * 32;
    const long gm = bm0 + row;
    bf16x8 v = *(const bf16x8*)&tile[row * TPAD + pc];
    if (EPI == 1) {
      if (hside) *(bf16x8*)&out0[gm * H_ + bn0 + pc] = v;
      else       *(bf16x8*)&out1[gm * H_ + (bn0 - H_) + pc] = v;
    } else {
      bf16x8 hb = *(const bf16x8*)&hbuf[gm * H_ + bn0 + pc];
      bf16x8 o;
#pragma unroll
      for (int k = 0; k < 8; ++k) {
        float s = (float)v[k] + (float)hb[k];
        o[k] = (bf16)fsilu(s);
      }
      *(bf16x8*)&out0[gm * H_ + bn0 + pc] = o;
      *(bf16x8*)&tile[row * TPAD + pc] = o;     // keep u in LDS for fused scan
    }
  }

  // ---- fused scan1 (EPI==2): per-chunk (A,B) reduction from the u tile ----
  if constexpr (EPI == 2) {
    __syncthreads();
    const int c_idx = t >> 7;                   // 0..3 (4 chunks per 128-row tile)
    const int col   = t & 127;
    const int gcol  = bn0 + col;
    const int bIdx  = bm0 >> 12;                // / S_
    const int s0    = bm0 & (S_ - 1);
    const int chunk = (s0 >> 5) + c_idx;        // global chunk within batch
    const int* mrow = mask + bIdx * S_ + s0 + c_idx * 32;
    const float aexp = RCPF(1.f + EXP2F(L2E * A_log[gcol]));  // sigmoid(-A_log)
    const float bp = Bp[gcol];
    const bf16* grow = gbuf + (long)(bm0 + c_idx * 32) * H_ + gcol;
    float At = 1.f, Bt = 0.f;
#pragma unroll 4
    for (int sl = 0; sl < LCH; ++sl) {
      float uv = (float)tile[(c_idx * 32 + sl) * TPAD + col];
      float gv = (float)grow[(long)sl * H_];
      bool mm = mrow[sl] != 0;
      float a_s = mm ? gv * aexp : 1.f;
      float b_s = mm ? (1.f - gv) * (bp * uv) : 0.f;
      At = a_s * At;
      Bt = fmaf(a_s, Bt, b_s);
    }
    long o = ((long)chunk * B_ + bIdx) * H_ + gcol;
    Ac[o] = At; Bc[o] = Bt;
  }
}

// ---------------- depthwise conv K=3, 'same' zero pad, per-channel ----------------
__global__ void k_dwconv(const bf16* __restrict__ h, const float* __restrict__ dww,
                         const float* __restrict__ dwb, bf16* __restrict__ hc)
{
  long idx = (long)blockIdx.x * blockDim.x + threadIdx.x;   // BSH/8 threads
  long m = idx >> 6;                 // row (b*S+s)
  int h8 = ((int)idx & 63) << 3;     // h base
  int s = (int)(m & (S_ - 1));
  bf16x8 c0, c1, c2;
#pragma unroll
  for (int j = 0; j < 8; ++j) { c0[j] = (bf16)0.f; c2[j] = (bf16)0.f; }
  if (s > 0)        c0 = *(const bf16x8*)(h + (m - 1) * H_ + h8);
  c1 = *(const bf16x8*)(h + m * H_ + h8);
  if (s < S_ - 1)   c2 = *(const bf16x8*)(h + (m + 1) * H_ + h8);
  bf16x8 o;
#pragma unroll
  for (int j = 0; j < 8; ++j) {
    int hh = h8 + j;
    float v = (float)c0[j] * dww[hh * 3 + 0] + (float)c1[j] * dww[hh * 3 + 1]
            + (float)c2[j] * dww[hh * 3 + 2] + dwb[hh];
    o[j] = (bf16)v;
  }
  *(bf16x8*)(hc + m * H_ + h8) = o;
}

// ---------------- chunked linear scan (passes 2 and 3) ----------------
// state_s = A_s*state + B_s ; A_s = m? g*aexp : 1 ; B_s = m? (1-g)*Bp*u : 0
// y_seq[s] = state_s * Cp  (invariant: last == state*Cp, both init 0)

__global__ __launch_bounds__(256)
void k_scan2(const float* __restrict__ Ac, const float* __restrict__ Bc,
             float* __restrict__ Sin)
{
  int tid = blockIdx.x * 256 + threadIdx.x;   // 0..B_*H_-1
  int b = tid >> 9, h = tid & (H_ - 1);
  const long stride = (long)B_ * H_;
  long o = (long)b * H_ + h;
  float st = 0.f;
  float a = Ac[o], bb = Bc[o];                // software pipeline: load c+1 during fma c
  for (int c = 0; c < CCH; ++c) {
    float an = 0.f, bn = 0.f;
    if (c + 1 < CCH) { an = Ac[o + stride]; bn = Bc[o + stride]; }
    Sin[o] = st;
    st = fmaf(a, st, bb);
    a = an; bb = bn; o += stride;
  }
}

__global__ __launch_bounds__(512)
void k_scan3(const bf16* __restrict__ u, const bf16* __restrict__ g,
             const int* __restrict__ mask, const float* __restrict__ A_log,
             const float* __restrict__ Bp, const float* __restrict__ Cp,
             const float* __restrict__ Sin,
             const float* __restrict__ ln_g, const float* __restrict__ ln_b,
             float* __restrict__ out)
{
  __shared__ float ylds[LCH][H_];   // 32*512*4 = 64 KB
  int c = blockIdx.x, b = blockIdx.y, h = threadIdx.x;
  float aexp = 1.f / (1.f + expf(A_log[h]));
  float bp = Bp[h], cp = Cp[h];
  float st = Sin[((long)c * B_ + b) * H_ + h];
  long base = ((long)b * S_ + (long)c * LCH) * H_ + h;
  const int* mrow = mask + b * S_ + c * LCH;
  for (int sl = 0; sl < LCH; ++sl) {
    float uv = (float)u[base + (long)sl * H_];
    float gv = (float)g[base + (long)sl * H_];
    bool mm = mrow[sl] != 0;
    float a_s = mm ? gv * aexp : 1.f;
    float b_s = mm ? (1.f - gv) * (bp * uv) : 0.f;
    st = fmaf(a_s, st, b_s);
    ylds[sl][h] = st * cp;
  }
  __syncthreads();
  // fused LayerNorm: 8 waves x 4 rows each
  int wv = h >> 6, ln = h & 63;
#pragma unroll
  for (int rr = 0; rr < 4; ++rr) {
    int row = wv * 4 + rr;
    float v[8];
    float sum = 0.f, sq = 0.f;
#pragma unroll
    for (int j = 0; j < 8; ++j) {
      v[j] = ylds[row][ln + 64 * j];
      sum += v[j]; sq += v[j] * v[j];
    }
#pragma unroll
    for (int off = 32; off; off >>= 1) {
      sum += __shfl_xor(sum, off);
      sq  += __shfl_xor(sq, off);
    }
    float mu = sum * (1.f / H_);
    float var = sq * (1.f / H_) - mu * mu;
    float rs = rsqrtf(var + 1e-5f);
    long ob = ((long)b * S_ + (long)c * LCH + row) * H_;
#pragma unroll
    for (int j = 0; j < 8; ++j) {
      int col = ln + 64 * j;
      out[ob + col] = (v[j] - mu) * rs * ln_g[col] + ln_b[col];
    }
  }
}

// ---------------- launch ----------------
extern "C" void kernel_launch(void* const* d_in, const int* in_sizes, int n_in,
                              void* d_out, int out_size, void* d_ws, size_t ws_size,
                              hipStream_t stream)
{
  const float* x      = (const float*)d_in[0];
  const int*   mask   = (const int*)d_in[1];
  const float* in_w   = (const float*)d_in[2];
  const float* in_b   = (const float*)d_in[3];
  const float* gate_w = (const float*)d_in[4];
  const float* gate_b = (const float*)d_in[5];
  const float* dw_w   = (const float*)d_in[6];
  const float* dw_b   = (const float*)d_in[7];
  const float* pw_w   = (const float*)d_in[8];
  const float* pw_b   = (const float*)d_in[9];
  const float* ln_g   = (const float*)d_in[10];
  const float* ln_b   = (const float*)d_in[11];
  const float* A_log  = (const float*)d_in[12];
  const float* Bp     = (const float*)d_in[13];
  const float* Cp     = (const float*)d_in[14];

  // workspace layout (needs ~316 MB)
  char* ws = (char*)d_ws;
  bf16*  xb  = (bf16*)(ws + 0L);           // 33,554,432 B
  bf16*  h   = (bf16*)(ws + 33554432L);    // 67,108,864 B
  bf16*  hc  = (bf16*)(ws + 100663296L);   // 67,108,864 B
  bf16*  u   = (bf16*)(ws + 167772160L);   // 67,108,864 B
  bf16*  g   = (bf16*)(ws + 234881024L);   // 67,108,864 B
  bf16*  w1  = (bf16*)(ws + 301989888L);   // 524,288 B (in_w ++ gate_w)
  bf16*  pw  = (bf16*)(ws + 302514176L);   // 524,288 B
  float* Ac  = (float*)(ws + 303038464L);  // 4,194,304 B
  float* Bc  = (float*)(ws + 307232768L);  // 4,194,304 B
  float* Sin = (float*)(ws + 311427072L);  // 4,194,304 B -> end 315,621,376
  float* out = (float*)d_out;

  const int gemm_lds = 128 * TPAD * 2;     // 34816 B (covers 2x16KB staging too)

  k_cast_x<<<8192, 256, 0, stream>>>(x, xb, (int)(BSD_ / 8));
  k_cast_w<<<2048, 256, 0, stream>>>(in_w, gate_w, pw_w, w1, pw);
  // proj GEMM: M=65536, N=1024 (h | g), K=256
  k_gemm<256, 1><<<512 * 8, 512, gemm_lds, stream>>>(
      xb, w1, mask, in_b, gate_b, nullptr, nullptr, nullptr, nullptr,
      nullptr, nullptr, h, g, 8);
  k_dwconv<<<16384, 256, 0, stream>>>(h, dw_w, dw_b, hc);
  // pointwise GEMM: M=65536, N=512, K=512  (+ fused scan1)
  k_gemm<512, 2><<<512 * 4, 512, gemm_lds, stream>>>(
      hc, pw, mask, pw_b, nullptr, h, g, A_log, Bp,
      Ac, Bc, u, nullptr, 4);
  k_scan2<<<32, 256, 0, stream>>>(Ac, Bc, Sin);
  k_scan3<<<dim3(CCH, B_), 512, 0, stream>>>(u, g, mask, A_log, Bp, Cp, Sin, ln_g, ln_b, out);
}

// Round 8
// 326.408 us; speedup vs baseline: 1.1500x; 1.1500x over previous
//
#include <hip/hip_runtime.h>
#include <hip/hip_bf16.h>
#include <math.h>

// Problem dims
#define B_  16
#define S_  4096
#define D_  256
#define H_  512
#define BS_ 65536           // B_*S_
#define BSH_ 33554432L      // BS_*H_
#define BSD_ 16777216L      // BS_*D_
#define CCH 128             // scan chunks
#define LCH 32              // chunk length (CCH*LCH == S_)
#define TPAD 136            // epilogue tile stride (272B row, 16B-aligned)

typedef __bf16 bf16;
typedef __bf16 bf16x8 __attribute__((ext_vector_type(8)));
typedef float  f32x4  __attribute__((ext_vector_type(4)));

#define AS1 __attribute__((address_space(1)))
#define AS3 __attribute__((address_space(3)))

__device__ __forceinline__ void gload_lds16(const void* g, void* l) {
  __builtin_amdgcn_global_load_lds((const AS1 void*)g, (AS3 void*)l, 16, 0, 0);
}

// ---- fast transcendentals (v_exp_f32 / v_rcp_f32; ~1ulp f32, fine for bf16 out) ----
#if __has_builtin(__builtin_amdgcn_exp2f)
#define EXP2F __builtin_amdgcn_exp2f
#else
#define EXP2F exp2f
#endif
#if __has_builtin(__builtin_amdgcn_rcpf)
#define RCPF __builtin_amdgcn_rcpf
#else
#define RCPF(x) (1.f/(x))
#endif
#define L2E 1.4426950408889634f

__device__ __forceinline__ float fsigmoid(float x) {
  return RCPF(1.f + EXP2F(-L2E * x));          // saturates to 0/1, no NaN
}
__device__ __forceinline__ float ftanh(float x) {
  return 2.f * RCPF(1.f + EXP2F(-2.f * L2E * x)) - 1.f;  // no NaN at +/-inf
}
__device__ __forceinline__ float fsilu(float x) {
  return x * RCPF(1.f + EXP2F(-L2E * x));
}

// ---------------- casts ----------------
__global__ void k_cast_x(const float* __restrict__ x, bf16* __restrict__ xb, int n8) {
  int i = blockIdx.x * blockDim.x + threadIdx.x;
  if (i >= n8) return;
  const float4* p = (const float4*)x + (long)i * 2;
  float4 a = p[0], b = p[1];
  bf16x8 o;
  o[0]=(bf16)a.x; o[1]=(bf16)a.y; o[2]=(bf16)a.z; o[3]=(bf16)a.w;
  o[4]=(bf16)b.x; o[5]=(bf16)b.y; o[6]=(bf16)b.z; o[7]=(bf16)b.w;
  ((bf16x8*)xb)[i] = o;
}

__global__ void k_cast_w(const float* __restrict__ in_w, const float* __restrict__ gate_w,
                         const float* __restrict__ pw_w,
                         bf16* __restrict__ w1, bf16* __restrict__ pw) {
  int i = blockIdx.x * blockDim.x + threadIdx.x;
  const int HD = H_ * D_;           // 131072
  if (i < HD)            w1[i] = (bf16)in_w[i];
  else if (i < 2 * HD)   w1[i] = (bf16)gate_w[i - HD];
  else {
    int j = i - 2 * HD;
    if (j < H_ * H_)     pw[j] = (bf16)pw_w[j];
  }
}

// ---------------- GEMM: 128x128 tile, BK=32, 8 waves (512 thr) ----------------
// Occupancy-first: per-wave acc = 4x2 frags (32 AGPR). K-loop: 2-deep LDS
// double-buffer with counted vmcnt + raw s_barrier.
// EPI==1: proj epilogue (h/g). EPI==2: pointwise u epilogue + FUSED scan1.
template<int KDIM, int EPI>
__global__ __launch_bounds__(512, 5)
void k_gemm(const bf16* __restrict__ A, const bf16* __restrict__ Bw,
            const int* __restrict__ mask,
            const float* __restrict__ bias0, const float* __restrict__ bias1,
            const bf16* __restrict__ hbuf, const bf16* __restrict__ gbuf,
            const float* __restrict__ A_log, const float* __restrict__ Bp,
            float* __restrict__ Ac, float* __restrict__ Bc,
            bf16* __restrict__ out0, bf16* __restrict__ out1, int Ntiles)
{
  extern __shared__ char smem_raw[];            // 34816 B (2x16KB staging | epi tile)
  bf16* tile = (bf16*)smem_raw;

  const int t = threadIdx.x;
  const int w = t >> 6, lane = t & 63;
  const int nwg = gridDim.x;                    // XCD-aware swizzle (nwg % 8 == 0)
  const int wg = (blockIdx.x & 7) * (nwg >> 3) + (blockIdx.x >> 3);
  const int bn0 = (wg % Ntiles) * 128;
  const int bm0 = (wg / Ntiles) * 128;
  const int wm = w >> 2, wn = w & 3;            // 2 x 4 wave grid: 64-row x 32-col
  const int fr = lane & 15, kq = lane >> 4;
  constexpr int NT = KDIM / 32;                 // 8 (proj) / 16 (pw)

  // staging: thread t covers row t>>2 (0..127), k-seg (t&3)*8; LDS linear t*8 elems
  const bf16* Ag = A  + (long)(bm0 + (t >> 2)) * KDIM + (t & 3) * 8;
  const bf16* Bg = Bw + (long)(bn0 + (t >> 2)) * KDIM + (t & 3) * 8;

  f32x4 acc[4][2];
#pragma unroll
  for (int i = 0; i < 4; ++i)
#pragma unroll
    for (int j = 0; j < 2; ++j) acc[i][j] = (f32x4){0.f, 0.f, 0.f, 0.f};

  // stage k-tile tt into buffer tt&1 (A then B: 2 vmem ops per thread)
#define STAGE(tt)                                                           \
  { char* _b = smem_raw + ((tt) & 1) * 16384;                               \
    gload_lds16(Ag + (tt) * 32, (bf16*)_b + t * 8);                         \
    gload_lds16(Bg + (tt) * 32, (bf16*)(_b + 8192) + t * 8); }

  STAGE(0); STAGE(1);                           // 4 ops in flight

#pragma unroll
  for (int kt = 0; kt < NT; ++kt) {
    // own tile-kt loads (2) complete; tile kt+1's (2) may remain in flight
    if (kt + 1 < NT) asm volatile("s_waitcnt vmcnt(2)" ::: "memory");
    else             asm volatile("s_waitcnt vmcnt(0)" ::: "memory");
    __builtin_amdgcn_s_barrier();               // buf[kt&1] staged by ALL waves

    const bf16* As = (const bf16*)(smem_raw + (kt & 1) * 16384);
    const bf16* Bs = As + 4096;
    bf16x8 af[4], bfr[2];
#pragma unroll
    for (int mi = 0; mi < 4; ++mi)
      af[mi] = *(const bf16x8*)&As[(wm * 64 + mi * 16 + fr) * 32 + kq * 8];
#pragma unroll
    for (int ni = 0; ni < 2; ++ni)
      bfr[ni] = *(const bf16x8*)&Bs[(wn * 32 + ni * 16 + fr) * 32 + kq * 8];

    asm volatile("s_waitcnt lgkmcnt(0)" ::: "memory");  // own reads in regs
    __builtin_amdgcn_s_barrier();               // all waves' reads done -> buf reusable

    if (kt + 2 < NT) STAGE(kt + 2);             // refill freed buffer

#pragma unroll
    for (int mi = 0; mi < 4; ++mi)
#pragma unroll
      for (int ni = 0; ni < 2; ++ni)
        acc[mi][ni] = __builtin_amdgcn_mfma_f32_16x16x32_bf16(af[mi], bfr[ni], acc[mi][ni], 0, 0, 0);
  }
#undef STAGE

  __syncthreads();   // staging reads done everywhere before tile overwrite

  // ---- epilogue phase 1: activate + scatter into LDS tile ----
  const bool hside = (EPI != 1) || (bn0 < H_);
#pragma unroll
  for (int mi = 0; mi < 4; ++mi) {
#pragma unroll
    for (int rr = 0; rr < 4; ++rr) {
      const int row = wm * 64 + mi * 16 + kq * 4 + rr;
      const int gm = bm0 + row;
      float mf = 1.f;
      if (EPI == 1) mf = (mask[gm] != 0) ? 1.f : 0.f;
#pragma unroll
      for (int ni = 0; ni < 2; ++ni) {
        const int col = wn * 32 + ni * 16 + fr;
        float c = acc[mi][ni][rr];
        float val;
        if (EPI == 1) {
          const int gn = bn0 + col;
          val = hside ? ftanh(c + bias0[gn]) * mf
                      : fsigmoid(c + bias1[gn - H_]);
        } else {
          val = c + bias0[bn0 + col];   // defer hbuf add + silu to phase 2
        }
        tile[row * TPAD + col] = (bf16)val;
      }
    }
  }
  __syncthreads();

  // ---- epilogue phase 2: coalesced readback + wide store ----
  const int pr = t >> 4;            // 0..31
  const int pc = (t & 15) * 8;      // col element base
#pragma unroll
  for (int rr = 0; rr < 4; ++rr) {
    const int row = pr + rr * 32;
    const long gm = bm0 + row;
    bf16x8 v = *(const bf16x8*)&tile[row * TPAD + pc];
    if (EPI == 1) {
      if (hside) *(bf16x8*)&out0[gm * H_ + bn0 + pc] = v;
      else       *(bf16x8*)&out1[gm * H_ + (bn0 - H_) + pc] = v;
    } else {
      bf16x8 hb = *(const bf16x8*)&hbuf[gm * H_ + bn0 + pc];
      bf16x8 o;
#pragma unroll
      for (int k = 0; k < 8; ++k) {
        float s = (float)v[k] + (float)hb[k];
        o[k] = (bf16)fsilu(s);
      }
      *(bf16x8*)&out0[gm * H_ + bn0 + pc] = o;
      *(bf16x8*)&tile[row * TPAD + pc] = o;     // keep u in LDS for fused scan
    }
  }

  // ---- fused scan1 (EPI==2): per-chunk (A,B) reduction from the u tile ----
  if constexpr (EPI == 2) {
    __syncthreads();
    const int c_idx = t >> 7;                   // 0..3 (4 chunks per 128-row tile)
    const int col   = t & 127;
    const int gcol  = bn0 + col;
    const int bIdx  = bm0 >> 12;                // / S_
    const int s0    = bm0 & (S_ - 1);
    const int chunk = (s0 >> 5) + c_idx;        // global chunk within batch
    const int* mrow = mask + bIdx * S_ + s0 + c_idx * 32;
    const float aexp = RCPF(1.f + EXP2F(L2E * A_log[gcol]));  // sigmoid(-A_log)
    const float bp = Bp[gcol];
    const bf16* grow = gbuf + (long)(bm0 + c_idx * 32) * H_ + gcol;
    float At = 1.f, Bt = 0.f;
#pragma unroll 4
    for (int sl = 0; sl < LCH; ++sl) {
      float uv = (float)tile[(c_idx * 32 + sl) * TPAD + col];
      float gv = (float)grow[(long)sl * H_];
      bool mm = mrow[sl] != 0;
      float a_s = mm ? gv * aexp : 1.f;
      float b_s = mm ? (1.f - gv) * (bp * uv) : 0.f;
      At = a_s * At;
      Bt = fmaf(a_s, Bt, b_s);
    }
    long o = ((long)chunk * B_ + bIdx) * H_ + gcol;
    Ac[o] = At; Bc[o] = Bt;
  }
}

// ---------------- depthwise conv K=3, 'same' zero pad, per-channel ----------------
__global__ void k_dwconv(const bf16* __restrict__ h, const float* __restrict__ dww,
                         const float* __restrict__ dwb, bf16* __restrict__ hc)
{
  long idx = (long)blockIdx.x * blockDim.x + threadIdx.x;   // BSH/8 threads
  long m = idx >> 6;                 // row (b*S+s)
  int h8 = ((int)idx & 63) << 3;     // h base
  int s = (int)(m & (S_ - 1));
  bf16x8 c0, c1, c2;
#pragma unroll
  for (int j = 0; j < 8; ++j) { c0[j] = (bf16)0.f; c2[j] = (bf16)0.f; }
  if (s > 0)        c0 = *(const bf16x8*)(h + (m - 1) * H_ + h8);
  c1 = *(const bf16x8*)(h + m * H_ + h8);
  if (s < S_ - 1)   c2 = *(const bf16x8*)(h + (m + 1) * H_ + h8);
  bf16x8 o;
#pragma unroll
  for (int j = 0; j < 8; ++j) {
    int hh = h8 + j;
    float v = (float)c0[j] * dww[hh * 3 + 0] + (float)c1[j] * dww[hh * 3 + 1]
            + (float)c2[j] * dww[hh * 3 + 2] + dwb[hh];
    o[j] = (bf16)v;
  }
  *(bf16x8*)(hc + m * H_ + h8) = o;
}

// ---------------- chunked linear scan (passes 2 and 3) ----------------
// state_s = A_s*state + B_s ; A_s = m? g*aexp : 1 ; B_s = m? (1-g)*Bp*u : 0
// y_seq[s] = state_s * Cp  (invariant: last == state*Cp, both init 0)

__global__ __launch_bounds__(256)
void k_scan2(const float* __restrict__ Ac, const float* __restrict__ Bc,
             float* __restrict__ Sin)
{
  int tid = blockIdx.x * 256 + threadIdx.x;   // 0..B_*H_-1
  int b = tid >> 9, h = tid & (H_ - 1);
  const long stride = (long)B_ * H_;
  long o = (long)b * H_ + h;
  float st = 0.f;
  float a = Ac[o], bb = Bc[o];                // software pipeline: load c+1 during fma c
  for (int c = 0; c < CCH; ++c) {
    float an = 0.f, bn = 0.f;
    if (c + 1 < CCH) { an = Ac[o + stride]; bn = Bc[o + stride]; }
    Sin[o] = st;
    st = fmaf(a, st, bb);
    a = an; bb = bn; o += stride;
  }
}

// Register-resident scan3 + fused LayerNorm. One wave per (b, chunk):
// lane owns 8 consecutive h (bf16x8 loads, 8-way ILP recurrence); LN via
// 6-step __shfl_xor over the wave; no LDS; coalesced float4 stores.
__global__ __launch_bounds__(256)
void k_scan3(const bf16* __restrict__ u, const bf16* __restrict__ g,
             const int* __restrict__ mask, const float* __restrict__ A_log,
             const float* __restrict__ Bp, const float* __restrict__ Cp,
             const float* __restrict__ Sin,
             const float* __restrict__ ln_g, const float* __restrict__ ln_b,
             float* __restrict__ out)
{
  const int wv = threadIdx.x >> 6, lane = threadIdx.x & 63;
  const int c = blockIdx.x * 4 + wv;          // chunk
  const int b = blockIdx.y;
  const int h0 = lane * 8;

  // per-h params (8 channels per lane), hoisted
  float aexp[8], bp[8], cp[8], lg[8], lb[8], st[8];
#pragma unroll
  for (int j = 0; j < 8; ++j) {
    aexp[j] = RCPF(1.f + EXP2F(L2E * A_log[h0 + j]));  // sigmoid(-A_log)
    bp[j] = Bp[h0 + j]; cp[j] = Cp[h0 + j];
    lg[j] = ln_g[h0 + j]; lb[j] = ln_b[h0 + j];
    st[j] = Sin[((long)c * B_ + b) * H_ + h0 + j];
  }

  const long base = ((long)b * S_ + (long)c * LCH) * H_ + h0;
  const int* mrow = mask + b * S_ + c * LCH;

  bf16x8 uv = *(const bf16x8*)(u + base);
  bf16x8 gv = *(const bf16x8*)(g + base);
  int mm = mrow[0];

  for (int sl = 0; sl < LCH; ++sl) {
    bf16x8 un, gn; int mn = 0;
    if (sl + 1 < LCH) {                        // prefetch next row under compute
      un = *(const bf16x8*)(u + base + (long)(sl + 1) * H_);
      gn = *(const bf16x8*)(g + base + (long)(sl + 1) * H_);
      mn = mrow[sl + 1];
    }
    const bool m = mm != 0;
    float y[8], sum = 0.f, sq = 0.f;
#pragma unroll
    for (int j = 0; j < 8; ++j) {
      float uu = (float)uv[j], gg = (float)gv[j];
      float a_s = m ? gg * aexp[j] : 1.f;
      float b_s = m ? (1.f - gg) * (bp[j] * uu) : 0.f;
      st[j] = fmaf(a_s, st[j], b_s);
      y[j] = st[j] * cp[j];
      sum += y[j];
      sq = fmaf(y[j], y[j], sq);
    }
#pragma unroll
    for (int off = 32; off; off >>= 1) {
      sum += __shfl_xor(sum, off);
      sq  += __shfl_xor(sq, off);
    }
    const float mu = sum * (1.f / H_);
    const float var = sq * (1.f / H_) - mu * mu;
    const float rs = rsqrtf(var + 1e-5f);
    const long ob = base + (long)sl * H_;
    f32x4 o0, o1;
#pragma unroll
    for (int j = 0; j < 4; ++j) o0[j] = (y[j] - mu) * rs * lg[j] + lb[j];
#pragma unroll
    for (int j = 0; j < 4; ++j) o1[j] = (y[4 + j] - mu) * rs * lg[4 + j] + lb[4 + j];
    *(f32x4*)(out + ob) = o0;
    *(f32x4*)(out + ob + 4) = o1;
    uv = un; gv = gn; mm = mn;
  }
}

// ---------------- launch ----------------
extern "C" void kernel_launch(void* const* d_in, const int* in_sizes, int n_in,
                              void* d_out, int out_size, void* d_ws, size_t ws_size,
                              hipStream_t stream)
{
  const float* x      = (const float*)d_in[0];
  const int*   mask   = (const int*)d_in[1];
  const float* in_w   = (const float*)d_in[2];
  const float* in_b   = (const float*)d_in[3];
  const float* gate_w = (const float*)d_in[4];
  const float* gate_b = (const float*)d_in[5];
  const float* dw_w   = (const float*)d_in[6];
  const float* dw_b   = (const float*)d_in[7];
  const float* pw_w   = (const float*)d_in[8];
  const float* pw_b   = (const float*)d_in[9];
  const float* ln_g   = (const float*)d_in[10];
  const float* ln_b   = (const float*)d_in[11];
  const float* A_log  = (const float*)d_in[12];
  const float* Bp     = (const float*)d_in[13];
  const float* Cp     = (const float*)d_in[14];

  // workspace layout (needs ~316 MB)
  char* ws = (char*)d_ws;
  bf16*  xb  = (bf16*)(ws + 0L);           // 33,554,432 B
  bf16*  h   = (bf16*)(ws + 33554432L);    // 67,108,864 B
  bf16*  hc  = (bf16*)(ws + 100663296L);   // 67,108,864 B
  bf16*  u   = (bf16*)(ws + 167772160L);   // 67,108,864 B
  bf16*  g   = (bf16*)(ws + 234881024L);   // 67,108,864 B
  bf16*  w1  = (bf16*)(ws + 301989888L);   // 524,288 B (in_w ++ gate_w)
  bf16*  pw  = (bf16*)(ws + 302514176L);   // 524,288 B
  float* Ac  = (float*)(ws + 303038464L);  // 4,194,304 B
  float* Bc  = (float*)(ws + 307232768L);  // 4,194,304 B
  float* Sin = (float*)(ws + 311427072L);  // 4,194,304 B -> end 315,621,376
  float* out = (float*)d_out;

  const int gemm_lds = 128 * TPAD * 2;     // 34816 B (covers 2x16KB staging too)

  k_cast_x<<<8192, 256, 0, stream>>>(x, xb, (int)(BSD_ / 8));
  k_cast_w<<<2048, 256, 0, stream>>>(in_w, gate_w, pw_w, w1, pw);
  // proj GEMM: M=65536, N=1024 (h | g), K=256
  k_gemm<256, 1><<<512 * 8, 512, gemm_lds, stream>>>(
      xb, w1, mask, in_b, gate_b, nullptr, nullptr, nullptr, nullptr,
      nullptr, nullptr, h, g, 8);
  k_dwconv<<<16384, 256, 0, stream>>>(h, dw_w, dw_b, hc);
  // pointwise GEMM: M=65536, N=512, K=512  (+ fused scan1)
  k_gemm<512, 2><<<512 * 4, 512, gemm_lds, stream>>>(
      hc, pw, mask, pw_b, nullptr, h, g, A_log, Bp,
      Ac, Bc, u, nullptr, 4);
  k_scan2<<<32, 256, 0, stream>>>(Ac, Bc, Sin);
  // scan3: one wave per (b, chunk); 4 waves/block -> grid (CCH/4, B)
  k_scan3<<<dim3(CCH / 4, B_), 256, 0, stream>>>(
      u, g, mask, A_log, Bp, Cp, Sin, ln_g, ln_b, out);
}